// Round 7
// baseline (62.975 us; speedup 1.0000x reference)
//
#include <hip/hip_runtime.h>

// Problem constants (from reference setup_inputs)
#define BB 8
#define QQ 30
#define DD 1500
#define EE 768
#define KK 11
#define WW 736      // (1500-30)/2 + 1
#define WIN 30
#define STR 2

#define ESPL 16     // E split count (grid)
#define ECH 48      // e per split (12 float4)
#define NF4 (ECH / 4)
#define DT 256      // d-tile per block
#define NDSUP 6     // ceil(1500/256)
#define RSTR 52     // LDS row stride in floats: 13 float4-slots (odd) -> BW-optimal b128

// ---------------------------------------------------------------------------
// Kernel 1: normalize q rows (240 rows): qn = qe / max(||qe||, 1e-13)
// ---------------------------------------------------------------------------
__global__ __launch_bounds__(256) void skl_normq(
    const float* __restrict__ qe, float* __restrict__ qn)
{
    int wid = threadIdx.x >> 6, lane = threadIdx.x & 63;
    int row = blockIdx.x * 4 + wid;
    if (row >= BB * QQ) return;
    const float4* p = (const float4*)(qe + (size_t)row * EE);
    float4 v[3];
    float ss = 0.f;
    #pragma unroll
    for (int k = 0; k < 3; k++) {
        v[k] = p[lane + 64 * k];
        ss += v[k].x * v[k].x + v[k].y * v[k].y + v[k].z * v[k].z + v[k].w * v[k].w;
    }
    #pragma unroll
    for (int off = 32; off >= 1; off >>= 1) ss += __shfl_xor(ss, off);
    float inv = 1.f / fmaxf(sqrtf(ss), 1e-13f);
    float4* o = (float4*)(qn + (size_t)row * EE);
    #pragma unroll
    for (int k = 0; k < 3; k++) {
        float4 w = v[k];
        w.x *= inv; w.y *= inv; w.z *= inv; w.w *= inv;
        o[lane + 64 * k] = w;
    }
}

// ---------------------------------------------------------------------------
// Kernel 2 (v4): cos partials, LDS-tiled GEMM.
// Block: 30 q x 256 d x 48 e; one-shot staging (2 barriers).
// Thread: 15 q x 2 d accumulators; d read as ds_read_b128 (2/iter),
// q as wave-uniform b128 broadcast (15/iter) -> LDS:VALU ~ 1:3.
// grid = (6 d-supertiles, 16 e-chunks, 8 batches) = 768 blocks = 3/CU.
// ---------------------------------------------------------------------------
__global__ __launch_bounds__(256) void skl_cos(
    const float* __restrict__ de,     // [8][1500][768]
    const float* __restrict__ qn,     // [240][768] normalized
    float* __restrict__ cpart,        // [16][240][1500]
    float* __restrict__ dssq)         // [16][8][1500]
{
    __shared__ float ds[DT][RSTR];    // 53.2 KB
    __shared__ float qs[QQ][RSTR];    // 6.2 KB
    int tid = threadIdx.x;
    int dsup = blockIdx.x;   // 0..5
    int ec   = blockIdx.y;   // 0..15
    int b    = blockIdx.z;   // 0..7
    int dbase = dsup * DT;
    int e0 = ec * ECH;

    // stage d: thread t owns row t (12 float4; lanes reuse their own 64B lines)
    {
        int drow = min(dbase + tid, DD - 1);
        const float4* src = (const float4*)(de + ((size_t)b * DD + drow) * EE + e0);
        #pragma unroll
        for (int k = 0; k < NF4; k++) {
            float4 v = src[k];
            *(float4*)&ds[tid][k * 4] = v;
        }
    }
    // stage q: 30 rows x 12 float4 = 360 slots
    for (int f = tid; f < QQ * NF4; f += 256) {
        int qrow = f / NF4, e4 = f - qrow * NF4;
        float4 v = *(const float4*)(qn + (size_t)(b * QQ + qrow) * EE + e0 + e4 * 4);
        *(float4*)&qs[qrow][e4 * 4] = v;
    }
    __syncthreads();

    int qh = tid >> 7;       // 0..1 -> q rows qh*15..qh*15+14
    int dslot = tid & 127;   // d = dbase+dslot, dbase+dslot+128

    float acc[15][2];
    #pragma unroll
    for (int q = 0; q < 15; q++) { acc[q][0] = 0.f; acc[q][1] = 0.f; }
    float ssq0 = 0.f, ssq1 = 0.f;

    #pragma unroll 4
    for (int e4 = 0; e4 < NF4; e4++) {
        float4 d0 = *(const float4*)&ds[dslot][e4 * 4];
        float4 d1 = *(const float4*)&ds[dslot + 128][e4 * 4];
        if (qh == 0) {
            ssq0 += d0.x * d0.x + d0.y * d0.y + d0.z * d0.z + d0.w * d0.w;
            ssq1 += d1.x * d1.x + d1.y * d1.y + d1.z * d1.z + d1.w * d1.w;
        }
        #pragma unroll
        for (int q = 0; q < 15; q++) {
            float4 qv = *(const float4*)&qs[qh * 15 + q][e4 * 4];
            acc[q][0] += qv.x * d0.x + qv.y * d0.y + qv.z * d0.z + qv.w * d0.w;
            acc[q][1] += qv.x * d1.x + qv.y * d1.y + qv.z * d1.z + qv.w * d1.w;
        }
    }

    int d0i = dbase + dslot, d1i = d0i + 128;
    int qb = b * QQ + qh * 15;
    #pragma unroll
    for (int q = 0; q < 15; q++) {
        if (d0i < DD) cpart[((size_t)ec * BB * QQ + qb + q) * DD + d0i] = acc[q][0];
        if (d1i < DD) cpart[((size_t)ec * BB * QQ + qb + q) * DD + d1i] = acc[q][1];
    }
    if (qh == 0) {
        if (d0i < DD) dssq[((size_t)ec * BB + b) * DD + d0i] = ssq0;
        if (d1i < DD) dssq[((size_t)ec * BB + b) * DD + d1i] = ssq1;
    }
}

// ---------------------------------------------------------------------------
// Kernel 3: sum cos partials, invd inline, RBF (f32 __expf) -> window sums
// (f32, float2 LDS reads) -> saturation (f32 fast pow) -> dense_w.
// Block per (b,q,chunk of 256 windows).
// ---------------------------------------------------------------------------
#define DCH 544    // max d-extent a chunk needs (2*255+29+1 = 540, padded)

__global__ __launch_bounds__(256) void skl_windows(
    const float* __restrict__ cpart,   // [16][240][1500]
    const float* __restrict__ dssq,    // [16][8][1500]
    const float* __restrict__ dmask,   // [8][1500]
    const float* __restrict__ qmask,   // [8][30]
    const float* __restrict__ qidfs,   // [240]
    const float* __restrict__ mu,      // [11]
    const float* __restrict__ sigma,   // [11]
    const float* __restrict__ w1, const float* __restrict__ b1,
    const float* __restrict__ w2, const float* __restrict__ b2,
    const float* __restrict__ w3, const float* __restrict__ b3,
    const float* __restrict__ dw,      // [11]
    float* __restrict__ pscore)        // [240][736]
{
    __shared__ float vf[KK][DCH];      // 23.9 KB
    __shared__ float fl[DCH];          // 2.2 KB

    int bid = blockIdx.x;     // 0..719
    int c  = bid % 3;
    int bq = bid / 3;         // 0..239
    int b  = bq / QQ;
    int tid = threadIdx.x;

    int dbase = 512 * c;
    int dcount = min(540, DD - dbase);
    int w = c * 256 + tid;
    bool active = (w < WW);

    float muL[KK], i2s[KK], dwL[KK];
    #pragma unroll
    for (int k = 0; k < KK; k++) {
        muL[k] = mu[k];
        float s = sigma[k];
        i2s[k] = 1.f / (2.f * s * s);
        dwL[k] = dw[k];
    }
    const float* dm = dmask + (size_t)b * DD + dbase;

    // phase 1: sum e-partials, invd, mask, 11 RBF values per d
    for (int i = tid; i < dcount; i += 256) {
        int dg = dbase + i;
        float s = 0.f, sq = 0.f;
        #pragma unroll
        for (int p = 0; p < ESPL; p++) {
            s  += cpart[((size_t)p * BB * QQ + bq) * DD + dg];
            sq += dssq[((size_t)p * BB + b) * DD + dg];
        }
        float invd = 1.f / fmaxf(sqrtf(sq), 1e-13f);
        float cc = s * invd;
        float m = dm[i];
        float ssum = 0.f;
        #pragma unroll
        for (int k = 0; k < KK; k++) {
            float diff = cc - muL[k];
            float val = __expf(-diff * diff * i2s[k]) * m;
            ssum += val;
            vf[k][i] = val;
        }
        fl[i] = (ssum != 0.f) ? 1.f : 0.f;
    }
    __syncthreads();

    // phase 2: per-window sums + saturation + dense_w
    if (active) {
        int dl = 2 * tid;     // window covers d-pairs tid..tid+14 (8B-aligned)
        float pk[KK];
        #pragma unroll
        for (int k = 0; k < KK; k++) pk[k] = 0.f;
        float lenf = 0.f;
        #pragma unroll
        for (int j2 = 0; j2 < WIN / 2; j2++) {
            float2 f2 = *(const float2*)&fl[dl + 2 * j2];
            lenf += f2.x + f2.y;
            #pragma unroll
            for (int k = 0; k < KK; k++) {
                float2 v2 = *(const float2*)&vf[k][dl + 2 * j2];
                pk[k] += v2.x + v2.y;
            }
        }
        float idf = fmaxf(qidfs[bq], 0.f);
        float sat1 = idf * w1[0] + lenf * w1[1] + b1[0];
        float sat2 = 1.f / (idf * w2[0] + lenf * w2[1] + b2[0]);
        float sat3 = idf * w3[0] + lenf * w3[1] + b3[0];
        float mult = qmask[bq] * (lenf > 0.f ? 1.f : 0.f);

        float acc = 0.f;
        #pragma unroll
        for (int k = 0; k < KK; k++) {
            float x = fmaxf(pk[k], 1e-10f);
            float p = exp2f(sat2 * __log2f(x));
            acc += (sat1 * p - sat3) * dwL[k];
        }
        pscore[(size_t)bq * WW + w] = acc * mult;
    }
}

// ---------------------------------------------------------------------------
// Kernel 4: per batch: sum over q (256 threads), then single-wave top-3
// argmax + pooling + gather.
// ---------------------------------------------------------------------------
__global__ __launch_bounds__(256) void skl_topk(
    const float* __restrict__ pscore,  // [240][736]
    const float* __restrict__ chunk,   // [15]
    float* __restrict__ out)           // [8]
{
    __shared__ float s0[WW];
    int b = blockIdx.x;
    int tid = threadIdx.x;

    for (int w = tid; w < WW; w += 256) {
        float s = 0.f;
        for (int q = 0; q < QQ; q++) s += pscore[(size_t)(b * QQ + q) * WW + w];
        s0[w] = (s == 0.f) ? -9900.f : s;
    }
    __syncthreads();

    if (tid < 64) {
        int lane = tid;
        float m[12];
        #pragma unroll
        for (int r = 0; r < 12; r++) {
            int w = lane + 64 * r;
            m[r] = (w < WW) ? s0[w] : -3.3e38f;
        }

        int best[3];
        for (int c = 0; c < 3; c++) {
            float bv = -3.3e38f;
            int bi = 1 << 30;
            #pragma unroll
            for (int r = 0; r < 12; r++) {
                int w = lane + 64 * r;
                if (w < WW && m[r] > bv) { bv = m[r]; bi = w; }
            }
            #pragma unroll
            for (int off = 32; off >= 1; off >>= 1) {
                float ov = __shfl_down(bv, off);
                int oi = __shfl_down(bi, off);
                if (ov > bv || (ov == bv && oi < bi)) { bv = ov; bi = oi; }
            }
            bi = __shfl(bi, 0);
            best[c] = bi;
            float pen = -10001.f - (float)c;
            #pragma unroll
            for (int r = 0; r < 12; r++) {
                int w = lane + 64 * r;
                int dd = w - bi; if (dd < 0) dd = -dd;
                if (w < WW && dd < 15) m[r] = pen;
            }
        }

        float contrib = 0.f;
        if (lane < 15) {
            int c = lane % 3;
            int g = lane / 3;
            const int offs[5] = {0, -1, 1, -2, 2};
            int nb = best[c] + offs[g];
            nb = min(max(nb, 0), WW - 1);
            float v = s0[nb];
            if (v <= -9900.f) v = 0.f;
            contrib = v * chunk[lane];
        }
        #pragma unroll
        for (int off = 32; off >= 1; off >>= 1) contrib += __shfl_down(contrib, off);
        if (lane == 0) out[b] = contrib;
    }
}

// ---------------------------------------------------------------------------
extern "C" void kernel_launch(void* const* d_in, const int* in_sizes, int n_in,
                              void* d_out, int out_size, void* d_ws, size_t ws_size,
                              hipStream_t stream) {
    const float* qe    = (const float*)d_in[0];   // (8,30,768)
    const float* de    = (const float*)d_in[1];   // (8,1500,768)
    const float* qmask = (const float*)d_in[2];   // (8,30)
    const float* dmask = (const float*)d_in[3];   // (8,1500)
    const float* qidfs = (const float*)d_in[4];   // (8,30,1)
    // d_in[5] = document_idfs (unused by reference)
    const float* mu    = (const float*)d_in[6];   // (11,)
    const float* sigma = (const float*)d_in[7];   // (11,)
    const float* w1    = (const float*)d_in[8];
    const float* b1    = (const float*)d_in[9];
    const float* w2    = (const float*)d_in[10];
    const float* b2    = (const float*)d_in[11];
    const float* w3    = (const float*)d_in[12];
    const float* b3    = (const float*)d_in[13];
    const float* dw    = (const float*)d_in[14];  // (1,11)
    const float* chunk = (const float*)d_in[15];  // (1,15)
    float* out = (float*)d_out;

    float* ws = (float*)d_ws;
    float* cpart  = ws;                    // 16*240*1500 = 5,760,000
    float* dssq   = ws + 5760000;          // 16*8*1500   =   192,000
    float* qn     = ws + 5952000;          // 240*768     =   184,320
    float* pscore = ws + 6136320;          // 240*736     =   176,640  (~25.3MB)

    skl_normq<<<60, 256, 0, stream>>>(qe, qn);
    skl_cos<<<dim3(NDSUP, ESPL, BB), 256, 0, stream>>>(de, qn, cpart, dssq);
    skl_windows<<<BB * QQ * 3, 256, 0, stream>>>(cpart, dssq, dmask, qmask, qidfs,
                                                 mu, sigma, w1, b1, w2, b2, w3, b3,
                                                 dw, pscore);
    skl_topk<<<BB, 256, 0, stream>>>(pscore, chunk, out);
}